// Round 2
// baseline (35.900 us; speedup 1.0000x reference)
//
#include <hip/hip_runtime.h>

// GALNLLLoss2d: fused 2x2 Cholesky-solve + log K1 Bessel NLL, mean-reduced.
// Inputs (f32): loc[B,2], m[B,2], L[B,2,2] (lower-tri, positive diag), x[B,2]
// Output: single f32 = -mean(log_prob)
// R2: float4 loads (2 rows/iter), log-folding (4 logf -> 2, 5 div -> 3).

#define C_LOG2   0.6931471805599453f
#define C_LOG2PI 1.8378770664093453f

__device__ __forceinline__ float gal_row(
    float lx, float ly, float mx, float my, float px, float py,
    float La, float Lb, float Lc)
{
    const float ia = 1.0f / La, ic = 1.0f / Lc;
    const float d0 = px - lx, d1 = py - ly;
    // y = L^{-1} v (forward substitution); v^T Sinv w = (L^{-1}v)·(L^{-1}w)
    const float ym0 = mx * ia;
    const float ym1 = (my - Lb * ym0) * ic;
    const float yx0 = d0 * ia;
    const float yx1 = (d1 - Lb * yx0) * ic;
    const float qm  = ym0 * ym0 + ym1 * ym1;   // m^T Sinv m
    const float qx  = yx0 * yx0 + yx1 * yx1;   // diff^T Sinv diff
    const float qxm = yx0 * ym0 + yx1 * ym1;   // diff^T Sinv m
    const float s = 2.0f + qm;
    const float z = sqrtf(s * qx);

    // Branchless A&S 9.8.3/9.8.7/9.8.8 with clamped safe args.
    const float zs = fminf(z, 2.0f);
    // small: log(kve1)-z = log(zK1(z)) - log(z)
    float t = zs * 0.26666666666f;  // z/3.75
    t = t * t;
    const float i1 = zs * (0.5f + t * (0.87890594f + t * (0.51498869f
                   + t * (0.15084934f + t * (0.02658733f + t * (0.00301532f
                   + t * 0.00032411f))))));
    const float t2 = zs * zs * 0.25f;
    const float zk1 = zs * logf(zs * 0.5f) * i1 + 1.0f + t2 * (0.15443144f
                    + t2 * (-0.67278579f + t2 * (-0.18156897f
                    + t2 * (-0.01919402f + t2 * (-0.00110404f
                    + t2 * (-0.00004686f))))));
    // large: log(kve1)-z = log(poly) - 0.5*log(z) - z
    const float zl = fmaxf(z, 2.0f);
    const float u = 2.0f / zl;
    const float poly = 1.25331414f + u * (0.23498619f + u * (-0.03655620f
                     + u * (0.01504268f + u * (-0.00780353f + u * (0.00325614f
                     + u * (-0.00068245f))))));
    const bool small = (z <= 2.0f);
    // Fold: -log(a*c) + 0.5*log(qx/s) + log(kve1) - z
    //   small: = log( zk1 / (s*a*c) )                 [z/zs cancels]
    //   large: = log( poly*sqrt(z) / (s*a*c) ) - z
    const float arg = small ? zk1 : poly * sqrtf(z);
    const float tail = small ? 0.0f : z;
    return C_LOG2 + qxm - C_LOG2PI + logf(arg / (s * La * Lc)) - tail;
}

__global__ __launch_bounds__(256) void gal_main_kernel(
    const float4* __restrict__ loc4, const float4* __restrict__ m4,
    const float4* __restrict__ L4,   const float4* __restrict__ x4,
    double* __restrict__ partial, int npairs)
{
    double acc = 0.0;
    const int stride = gridDim.x * blockDim.x;
    for (int p = blockIdx.x * blockDim.x + threadIdx.x; p < npairs; p += stride) {
        const float4 l = loc4[p];
        const float4 mm = m4[p];
        const float4 xx = x4[p];
        const float4 LA = L4[2 * p];      // row 2p:   [a, 0, b, c]
        const float4 LB = L4[2 * p + 1];  // row 2p+1
        const float r0 = gal_row(l.x, l.y, mm.x, mm.y, xx.x, xx.y,
                                 LA.x, LA.z, LA.w);
        const float r1 = gal_row(l.z, l.w, mm.z, mm.w, xx.z, xx.w,
                                 LB.x, LB.z, LB.w);
        acc += (double)r0 + (double)r1;
    }
    #pragma unroll
    for (int off = 32; off > 0; off >>= 1)
        acc += __shfl_down(acc, off);
    __shared__ double smem[4];
    const int lane = threadIdx.x & 63;
    const int wid  = threadIdx.x >> 6;
    if (lane == 0) smem[wid] = acc;
    __syncthreads();
    if (threadIdx.x == 0)
        partial[blockIdx.x] = smem[0] + smem[1] + smem[2] + smem[3];
}

__global__ __launch_bounds__(256) void gal_final_kernel(
    const double* __restrict__ partial, int nblocks,
    float* __restrict__ out, double inv_n)
{
    double acc = 0.0;
    for (int i = threadIdx.x; i < nblocks; i += 256)
        acc += partial[i];
    #pragma unroll
    for (int off = 32; off > 0; off >>= 1)
        acc += __shfl_down(acc, off);
    __shared__ double smem[4];
    const int lane = threadIdx.x & 63;
    const int wid  = threadIdx.x >> 6;
    if (lane == 0) smem[wid] = acc;
    __syncthreads();
    if (threadIdx.x == 0)
        out[0] = (float)(-(smem[0] + smem[1] + smem[2] + smem[3]) * inv_n);
}

extern "C" void kernel_launch(void* const* d_in, const int* in_sizes, int n_in,
                              void* d_out, int out_size, void* d_ws, size_t ws_size,
                              hipStream_t stream) {
    const float* loc = (const float*)d_in[0];
    const float* m   = (const float*)d_in[1];
    const float* L   = (const float*)d_in[2];
    const float* x   = (const float*)d_in[3];
    const int n = in_sizes[0] / 2;       // B rows (B = 4,194,304, even)
    const int npairs = n / 2;

    int nblocks = 2048;  // 524288 threads, 4 pairs/thread via grid-stride
    const size_t need = (size_t)nblocks * sizeof(double);
    if (ws_size < need) nblocks = (int)(ws_size / sizeof(double));
    double* partial = (double*)d_ws;

    gal_main_kernel<<<nblocks, 256, 0, stream>>>(
        (const float4*)loc, (const float4*)m, (const float4*)L,
        (const float4*)x, partial, npairs);
    gal_final_kernel<<<1, 256, 0, stream>>>(partial, nblocks, (float*)d_out,
                                            1.0 / (double)n);
}